// Round 1
// baseline (619.316 us; speedup 1.0000x reference)
//
#include <hip/hip_runtime.h>
#include <math.h>

// Problem constants (C = RC = 1)
#define BB 2
#define SS 1024
#define DD 1024
#define NH 16
#define DH 64
#define MAXN 0.996f   // (1 - PROJ_EPS)/RC

__device__ __forceinline__ float xor_sum16(float v){
  v += __shfl_xor(v, 1, 64);
  v += __shfl_xor(v, 2, 64);
  v += __shfl_xor(v, 4, 64);
  v += __shfl_xor(v, 8, 64);
  return v;
}
__device__ __forceinline__ float xor_max16(float v){
  v = fmaxf(v, __shfl_xor(v, 1, 64));
  v = fmaxf(v, __shfl_xor(v, 2, 64));
  v = fmaxf(v, __shfl_xor(v, 4, 64));
  v = fmaxf(v, __shfl_xor(v, 8, 64));
  return v;
}

// ---------------- K1a: column norms of z + cosh/sinh(2r) ----------------
__global__ __launch_bounds__(256) void col_stats_kernel(
    const float* __restrict__ zq, const float* __restrict__ zk, const float* __restrict__ zv,
    const float* __restrict__ rq, const float* __restrict__ rk, const float* __restrict__ rv,
    float* __restrict__ zn, float* __restrict__ c2r, float* __restrict__ s2r)
{
  const int m = blockIdx.y;
  const float* z = (m == 0) ? zq : ((m == 1) ? zk : zv);
  const float* r = (m == 0) ? rq : ((m == 1) ? rk : rv);
  const int j = blockIdx.x * 256 + threadIdx.x;   // 0..1023
  float acc = 0.0f;
  for (int i = 0; i < DD; ++i) { float t = z[(size_t)i * DD + j]; acc = fmaf(t, t, acc); }
  float n = fmaxf(sqrtf(acc), 1e-15f);
  zn[m * DD + j] = n;
  float rr = 2.0f * r[j];
  c2r[m * DD + j] = coshf(rr);
  s2r[m * DD + j] = sinhf(rr);
}

// ---------------- K1b: per-row ||x||^2 ----------------
__global__ __launch_bounds__(256) void row_cx2_kernel(const float* __restrict__ x,
                                                      float* __restrict__ cx2)
{
  const int wave = threadIdx.x >> 6;
  const int lane = threadIdx.x & 63;
  const int row = blockIdx.x * 4 + wave;          // 2048 rows, grid 512
  const float* xr = x + (size_t)row * DD;
  float acc = 0.0f;
  for (int i = lane; i < DD; i += 64) { float t = xr[i]; acc = fmaf(t, t, acc); }
  #pragma unroll
  for (int m = 1; m < 64; m <<= 1) acc += __shfl_xor(acc, m, 64);
  if (lane == 0) cx2[row] = acc;
}

// ---------------- K2: fused GEMM (x@z) + Poincare-linear epilogue ----------------
// Tile: 64 rows x 64 cols (one head), BK=16, 256 threads, 4x4 micro-tile.
__global__ __launch_bounds__(256) void gemm_poincare_kernel(
    const float* __restrict__ x,
    const float* __restrict__ zq, const float* __restrict__ zk, const float* __restrict__ zv,
    const float* __restrict__ zn, const float* __restrict__ c2r, const float* __restrict__ s2r,
    const float* __restrict__ cx2,
    float* __restrict__ Q, float* __restrict__ K, float* __restrict__ GV,
    float* __restrict__ q2, float* __restrict__ k2, float* __restrict__ gm1)
{
  __shared__ float As[16][68];   // [k][m] (A transposed)
  __shared__ float Bs[16][68];   // [k][n]

  const int mat = blockIdx.z;
  const float* z = (mat == 0) ? zq : ((mat == 1) ? zk : zv);
  float* OutM   = (mat == 0) ? Q  : ((mat == 1) ? K  : GV);
  float* Stat   = (mat == 0) ? q2 : ((mat == 1) ? k2 : gm1);

  const int row0 = blockIdx.x * 64;
  const int head = blockIdx.y;
  const int tid = threadIdx.x;
  const int tx = tid & 15, ty = tid >> 4;

  const int mload = tid >> 2, kv = tid & 3;       // A-tile load mapping
  const int kload = tid >> 4, nv = tid & 15;      // B-tile load mapping

  float acc[4][4] = {};

  for (int k0 = 0; k0 < DD; k0 += 16) {
    __syncthreads();
    float4 av = *(const float4*)(x + (size_t)(row0 + mload) * DD + k0 + 4 * kv);
    As[4*kv+0][mload] = av.x; As[4*kv+1][mload] = av.y;
    As[4*kv+2][mload] = av.z; As[4*kv+3][mload] = av.w;
    float4 bv = *(const float4*)(z + (size_t)(k0 + kload) * DD + head * 64 + 4 * nv);
    *(float4*)&Bs[kload][4*nv] = bv;
    __syncthreads();
    #pragma unroll
    for (int k = 0; k < 16; ++k) {
      float4 a4 = *(float4*)&As[k][4*ty];
      float4 b4 = *(float4*)&Bs[k][4*tx];
      float a[4] = {a4.x, a4.y, a4.z, a4.w};
      float b[4] = {b4.x, b4.y, b4.z, b4.w};
      #pragma unroll
      for (int i = 0; i < 4; ++i)
        #pragma unroll
        for (int j = 0; j < 4; ++j)
          acc[i][j] = fmaf(a[i], b[j], acc[i][j]);
    }
  }

  // Poincare-linear epilogue: u -> w -> y = sinh(w), then per-head projection chain.
  float y[4][4];
  #pragma unroll
  for (int i = 0; i < 4; ++i) {
    const int row = row0 + 4 * ty + i;
    const float c2 = cx2[row];
    const float inv = 1.0f / fmaxf(1.0f - c2, 1e-15f);
    const float onec = 1.0f + c2;
    #pragma unroll
    for (int j = 0; j < 4; ++j) {
      const int col = head * 64 + 4 * tx + j;
      const float znv = zn[mat * DD + col];
      const float u = (2.0f * (acc[i][j] / znv) * c2r[mat * DD + col] - onec * s2r[mat * DD + col]) * inv;
      const float w = 2.0f * znv * asinhf(u);
      y[i][j] = sinhf(w);
    }
  }

  #pragma unroll
  for (int i = 0; i < 4; ++i) {
    // head-norm over the 64 cols: 4 local + 16-lane shuffle sum
    float n2 = y[i][0]*y[i][0] + y[i][1]*y[i][1] + y[i][2]*y[i][2] + y[i][3]*y[i][3];
    n2 = xor_sum16(n2);
    float n = fmaxf(sqrtf(n2), 1e-15f);
    float s1 = (n > MAXN) ? (MAXN / n) : 1.0f;        // project #1
    n2 = n2 * s1 * s1;
    float f = 1.0f / (1.0f + sqrtf(1.0f + n2));       // exp-map scaling
    float fs = s1 * f;
    n2 = n2 * f * f;
    float nb = fmaxf(sqrtf(n2), 1e-15f);
    float s2f = (nb > MAXN) ? (MAXN / nb) : 1.0f;     // project #2
    fs *= s2f;
    n2 = n2 * s2f * s2f;

    const int row = row0 + 4 * ty + i;
    const int b = row >> 10, s = row & 1023;
    const size_t bh = (size_t)(b * NH + head);
    const size_t outbase = (bh * SS + s) * DH + 4 * tx;
    float4 o;
    if (mat == 2) {
      const float gamma = 2.0f / fmaxf(1.0f - n2, 1e-15f);
      o.x = y[i][0]*fs*gamma; o.y = y[i][1]*fs*gamma; o.z = y[i][2]*fs*gamma; o.w = y[i][3]*fs*gamma;
      if (tx == 0) Stat[bh * SS + s] = gamma - 1.0f;
    } else {
      o.x = y[i][0]*fs; o.y = y[i][1]*fs; o.z = y[i][2]*fs; o.w = y[i][3]*fs;
      if (tx == 0) Stat[bh * SS + s] = n2;
    }
    *(float4*)(OutM + outbase) = o;
  }
}

// ---------------- K4: flash-style hyperbolic attention ----------------
// Block: 256 thr, 64 q-rows; loop over 16 k-tiles of 64. Online max; the softmax
// normalizer cancels in nomin/denom ratio so only (m, ctx, denom) are tracked.
__global__ __launch_bounds__(256) void flash_attn_kernel(
    const float* __restrict__ Q, const float* __restrict__ K, const float* __restrict__ GV,
    const float* __restrict__ q2a, const float* __restrict__ k2a, const float* __restrict__ gm1a,
    const float* __restrict__ mask, float* __restrict__ out)
{
  __shared__ float Qt[64][68];     // [d][r]
  __shared__ float KsPs[64][68];   // Ks: [d][t] during scores; reused as Ps: [t][r] for PV
  __shared__ float GVs[64][68];    // [t][d]
  __shared__ float k2s[64], gm1s[64], ms_[64];

  const int qt = blockIdx.x, h = blockIdx.y, b = blockIdx.z;
  const int tid = threadIdx.x, tx = tid & 15, ty = tid >> 4;
  const int bh = b * NH + h;
  const int r0 = qt * 64;
  const float* Qp  = Q  + (size_t)bh * SS * DH;
  const float* Kp  = K  + (size_t)bh * SS * DH;
  const float* GVp = GV + (size_t)bh * SS * DH;

  #pragma unroll
  for (int l = 0; l < 4; ++l) {
    int idx = tid + l * 256; int r = idx >> 4, dv = idx & 15;
    float4 v = *(const float4*)(Qp + (size_t)(r0 + r) * DH + 4 * dv);
    Qt[4*dv+0][r] = v.x; Qt[4*dv+1][r] = v.y; Qt[4*dv+2][r] = v.z; Qt[4*dv+3][r] = v.w;
  }
  float q2r[4], q1m[4];
  #pragma unroll
  for (int i = 0; i < 4; ++i) {
    q2r[i] = q2a[(size_t)bh * SS + r0 + 4 * ty + i];
    q1m[i] = 1.0f - q2r[i];
  }
  float mrow[4] = {-INFINITY, -INFINITY, -INFINITY, -INFINITY};
  float dden[4] = {0.0f, 0.0f, 0.0f, 0.0f};
  float ctx[4][4] = {};

  for (int kt = 0; kt < 16; ++kt) {
    const int t0 = kt * 64;
    __syncthreads();                               // A: KsPs/GVs free
    #pragma unroll
    for (int l = 0; l < 4; ++l) {
      int idx = tid + l * 256; int t = idx >> 4, dv = idx & 15;
      float4 v = *(const float4*)(Kp + (size_t)(t0 + t) * DH + 4 * dv);
      KsPs[4*dv+0][t] = v.x; KsPs[4*dv+1][t] = v.y; KsPs[4*dv+2][t] = v.z; KsPs[4*dv+3][t] = v.w;
      float4 g = *(const float4*)(GVp + (size_t)(t0 + t) * DH + 4 * dv);
      *(float4*)&GVs[t][4*dv] = g;
    }
    if (tid < 64) {
      k2s[tid]  = k2a[(size_t)bh * SS + t0 + tid];
      gm1s[tid] = gm1a[(size_t)bh * SS + t0 + tid];
      ms_[tid]  = mask[b * SS + t0 + tid];
    }
    __syncthreads();                               // B: tiles loaded

    // scores: QK^T
    float s[4][4] = {};
    #pragma unroll 8
    for (int d = 0; d < 64; ++d) {
      float4 a4 = *(float4*)&Qt[d][4*ty];
      float4 b4 = *(float4*)&KsPs[d][4*tx];
      float a[4] = {a4.x, a4.y, a4.z, a4.w};
      float bb[4] = {b4.x, b4.y, b4.z, b4.w};
      #pragma unroll
      for (int i = 0; i < 4; ++i)
        #pragma unroll
        for (int j = 0; j < 4; ++j)
          s[i][j] = fmaf(a[i], bb[j], s[i][j]);
    }

    // distance transform + online softmax state update
    float pv[4][4];
    #pragma unroll
    for (int i = 0; i < 4; ++i) {
      float sc[4];
      float rowmax = -INFINITY;
      #pragma unroll
      for (int j = 0; j < 4; ++j) {
        const float k2v = k2s[4*tx+j];
        const float num = fmaxf(q2r[i] - 2.0f * s[i][j] + k2v, 1e-15f);
        const float den = fmaxf(q1m[i] * (1.0f - k2v), 1e-15f);
        const float e = 2.0f * num / den;
        const float dist = log1pf(e + sqrtf(e * (e + 2.0f)));  // acosh(1+e)
        sc[j] = ms_[4*tx+j] - dist;
        rowmax = fmaxf(rowmax, sc[j]);
      }
      rowmax = xor_max16(rowmax);
      const float newm = fmaxf(mrow[i], rowmax);
      const float alpha = expf(mrow[i] - newm);
      mrow[i] = newm;
      float dpart = 0.0f;
      #pragma unroll
      for (int j = 0; j < 4; ++j) {
        const float p = expf(sc[j] - newm);
        pv[i][j] = p;
        dpart = fmaf(p, gm1s[4*tx+j], dpart);
      }
      dden[i] = dden[i] * alpha + dpart;
      #pragma unroll
      for (int j = 0; j < 4; ++j) ctx[i][j] *= alpha;
    }
    __syncthreads();                               // C: done reading Ks
    #pragma unroll
    for (int i = 0; i < 4; ++i)
      #pragma unroll
      for (int j = 0; j < 4; ++j)
        KsPs[4*tx+j][4*ty+i] = pv[i][j];           // Ps[t][r]
    __syncthreads();                               // D: Ps visible

    // PV: ctx += Ps^T (rows) x GVs
    #pragma unroll 8
    for (int t = 0; t < 64; ++t) {
      float4 p4 = *(float4*)&KsPs[t][4*ty];
      float4 g4 = *(float4*)&GVs[t][4*tx];
      float p[4] = {p4.x, p4.y, p4.z, p4.w};
      float g[4] = {g4.x, g4.y, g4.z, g4.w};
      #pragma unroll
      for (int i = 0; i < 4; ++i)
        #pragma unroll
        for (int j = 0; j < 4; ++j)
          ctx[i][j] = fmaf(p[i], g[j], ctx[i][j]);
    }
  }

  // epilogue: gyromidpoint normalization + project, write [B,S,H*dh]
  #pragma unroll
  for (int i = 0; i < 4; ++i) {
    float d = xor_sum16(dden[i]);
    d = fmaxf(d, 1e-10f);
    float tm[4];
    float sq = 0.0f;
    #pragma unroll
    for (int j = 0; j < 4; ++j) { tm[j] = ctx[i][j] / d; sq = fmaf(tm[j], tm[j], sq); }
    sq = xor_sum16(sq);
    const float f = 1.0f / (1.0f + sqrtf(fmaxf(1.0f - sq, 1e-15f)));
    const float n2 = sq * f * f;
    const float n = fmaxf(sqrtf(n2), 1e-15f);
    const float s2f = (n > MAXN) ? (MAXN / n) : 1.0f;
    const float fs = f * s2f;
    const int row = r0 + 4 * ty + i;
    float4 o; o.x = tm[0]*fs; o.y = tm[1]*fs; o.z = tm[2]*fs; o.w = tm[3]*fs;
    *(float4*)(out + ((size_t)(b * SS + row)) * DD + h * DH + 4 * tx) = o;
  }
}

// ---------------- host ----------------
extern "C" void kernel_launch(void* const* d_in, const int* in_sizes, int n_in,
                              void* d_out, int out_size, void* d_ws, size_t ws_size,
                              hipStream_t stream) {
  const float* hs   = (const float*)d_in[0];
  const float* mask = (const float*)d_in[1];
  const float* qz   = (const float*)d_in[2];
  const float* qr   = (const float*)d_in[3];
  const float* kz   = (const float*)d_in[4];
  const float* kr   = (const float*)d_in[5];
  const float* vz   = (const float*)d_in[6];
  const float* vr   = (const float*)d_in[7];
  float* out = (float*)d_out;

  float* ws = (float*)d_ws;
  const size_t nQKV = (size_t)BB * NH * SS * DH;   // 2,097,152
  const size_t nStat = (size_t)BB * NH * SS;       // 32,768
  float* Q   = ws;
  float* K   = Q + nQKV;
  float* GV  = K + nQKV;
  float* q2  = GV + nQKV;
  float* k2  = q2 + nStat;
  float* gm1 = k2 + nStat;
  float* zn  = gm1 + nStat;        // 3*1024
  float* c2r = zn + 3 * DD;
  float* s2r = c2r + 3 * DD;
  float* cx2 = s2r + 3 * DD;       // 2048

  col_stats_kernel<<<dim3(4, 3), 256, 0, stream>>>(qz, kz, vz, qr, kr, vr, zn, c2r, s2r);
  row_cx2_kernel<<<dim3(512), 256, 0, stream>>>(hs, cx2);
  gemm_poincare_kernel<<<dim3(32, 16, 3), 256, 0, stream>>>(
      hs, qz, kz, vz, zn, c2r, s2r, cx2, Q, K, GV, q2, k2, gm1);
  flash_attn_kernel<<<dim3(16, 16, 2), 256, 0, stream>>>(
      Q, K, GV, q2, k2, gm1, mask, out);
}

// Round 2
// 403.943 us; speedup vs baseline: 1.5332x; 1.5332x over previous
//
#include <hip/hip_runtime.h>
#include <math.h>

// Problem constants (C = RC = 1)
#define BB 2
#define SS 1024
#define DD 1024
#define NH 16
#define DH 64
#define MAXN 0.996f   // (1 - PROJ_EPS)/RC

typedef __attribute__((ext_vector_type(8))) short bf16x8;  // MFMA A/B frag (4 VGPRs)
typedef __attribute__((ext_vector_type(4))) float f32x4;   // MFMA C/D frag

__device__ __forceinline__ float xor_sum16(float v){
  v += __shfl_xor(v, 1, 64);
  v += __shfl_xor(v, 2, 64);
  v += __shfl_xor(v, 4, 64);
  v += __shfl_xor(v, 8, 64);
  return v;
}

__device__ __forceinline__ unsigned short f2bf(float x){
  unsigned u = __builtin_bit_cast(unsigned, x);
  unsigned r = u + 0x7FFFu + ((u >> 16) & 1u);   // RNE
  return (unsigned short)(r >> 16);
}
__device__ __forceinline__ float bf2f(unsigned short b){
  unsigned u = ((unsigned)b) << 16;
  return __builtin_bit_cast(float, u);
}

// ---------------- K1a: column norms of z + cosh/sinh(2r) ----------------
__global__ __launch_bounds__(256) void col_stats_kernel(
    const float* __restrict__ zq, const float* __restrict__ zk, const float* __restrict__ zv,
    const float* __restrict__ rq, const float* __restrict__ rk, const float* __restrict__ rv,
    float* __restrict__ zn, float* __restrict__ c2r, float* __restrict__ s2r)
{
  const int m = blockIdx.y;
  const float* z = (m == 0) ? zq : ((m == 1) ? zk : zv);
  const float* r = (m == 0) ? rq : ((m == 1) ? rk : rv);
  const int j = blockIdx.x * 256 + threadIdx.x;   // 0..1023
  float acc = 0.0f;
  for (int i = 0; i < DD; ++i) { float t = z[(size_t)i * DD + j]; acc = fmaf(t, t, acc); }
  float n = fmaxf(sqrtf(acc), 1e-15f);
  zn[m * DD + j] = n;
  float rr = 2.0f * r[j];
  c2r[m * DD + j] = coshf(rr);
  s2r[m * DD + j] = sinhf(rr);
}

// ---------------- K1b: per-row ||x||^2 ----------------
__global__ __launch_bounds__(256) void row_cx2_kernel(const float* __restrict__ x,
                                                      float* __restrict__ cx2)
{
  const int wave = threadIdx.x >> 6;
  const int lane = threadIdx.x & 63;
  const int row = blockIdx.x * 4 + wave;          // 2048 rows, grid 512
  const float* xr = x + (size_t)row * DD;
  float acc = 0.0f;
  for (int i = lane; i < DD; i += 64) { float t = xr[i]; acc = fmaf(t, t, acc); }
  #pragma unroll
  for (int m = 1; m < 64; m <<= 1) acc += __shfl_xor(acc, m, 64);
  if (lane == 0) cx2[row] = acc;
}

// ---------------- K2: fused GEMM (x@z) + Poincare-linear epilogue ----------------
__global__ __launch_bounds__(256) void gemm_poincare_kernel(
    const float* __restrict__ x,
    const float* __restrict__ zq, const float* __restrict__ zk, const float* __restrict__ zv,
    const float* __restrict__ zn, const float* __restrict__ c2r, const float* __restrict__ s2r,
    const float* __restrict__ cx2,
    float* __restrict__ Q, float* __restrict__ K, float* __restrict__ GV,
    float* __restrict__ q2, float* __restrict__ k2, float* __restrict__ gm1)
{
  __shared__ float As[16][68];   // [k][m] (A transposed)
  __shared__ float Bs[16][68];   // [k][n]

  const int mat = blockIdx.z;
  const float* z = (mat == 0) ? zq : ((mat == 1) ? zk : zv);
  float* OutM   = (mat == 0) ? Q  : ((mat == 1) ? K  : GV);
  float* Stat   = (mat == 0) ? q2 : ((mat == 1) ? k2 : gm1);

  const int row0 = blockIdx.x * 64;
  const int head = blockIdx.y;
  const int tid = threadIdx.x;
  const int tx = tid & 15, ty = tid >> 4;

  const int mload = tid >> 2, kv = tid & 3;       // A-tile load mapping
  const int kload = tid >> 4, nv = tid & 15;      // B-tile load mapping

  float acc[4][4] = {};

  for (int k0 = 0; k0 < DD; k0 += 16) {
    __syncthreads();
    float4 av = *(const float4*)(x + (size_t)(row0 + mload) * DD + k0 + 4 * kv);
    As[4*kv+0][mload] = av.x; As[4*kv+1][mload] = av.y;
    As[4*kv+2][mload] = av.z; As[4*kv+3][mload] = av.w;
    float4 bv = *(const float4*)(z + (size_t)(k0 + kload) * DD + head * 64 + 4 * nv);
    *(float4*)&Bs[kload][4*nv] = bv;
    __syncthreads();
    #pragma unroll
    for (int k = 0; k < 16; ++k) {
      float4 a4 = *(float4*)&As[k][4*ty];
      float4 b4 = *(float4*)&Bs[k][4*tx];
      float a[4] = {a4.x, a4.y, a4.z, a4.w};
      float b[4] = {b4.x, b4.y, b4.z, b4.w};
      #pragma unroll
      for (int i = 0; i < 4; ++i)
        #pragma unroll
        for (int j = 0; j < 4; ++j)
          acc[i][j] = fmaf(a[i], b[j], acc[i][j]);
    }
  }

  float y[4][4];
  #pragma unroll
  for (int i = 0; i < 4; ++i) {
    const int row = row0 + 4 * ty + i;
    const float c2 = cx2[row];
    const float inv = 1.0f / fmaxf(1.0f - c2, 1e-15f);
    const float onec = 1.0f + c2;
    #pragma unroll
    for (int j = 0; j < 4; ++j) {
      const int col = head * 64 + 4 * tx + j;
      const float znv = zn[mat * DD + col];
      const float u = (2.0f * (acc[i][j] / znv) * c2r[mat * DD + col] - onec * s2r[mat * DD + col]) * inv;
      const float w = 2.0f * znv * asinhf(u);
      y[i][j] = sinhf(w);
    }
  }

  #pragma unroll
  for (int i = 0; i < 4; ++i) {
    float n2 = y[i][0]*y[i][0] + y[i][1]*y[i][1] + y[i][2]*y[i][2] + y[i][3]*y[i][3];
    n2 = xor_sum16(n2);
    float n = fmaxf(sqrtf(n2), 1e-15f);
    float s1 = (n > MAXN) ? (MAXN / n) : 1.0f;        // project #1
    n2 = n2 * s1 * s1;
    float f = 1.0f / (1.0f + sqrtf(1.0f + n2));       // exp-map scaling
    float fs = s1 * f;
    n2 = n2 * f * f;
    float nb = fmaxf(sqrtf(n2), 1e-15f);
    float s2f = (nb > MAXN) ? (MAXN / nb) : 1.0f;     // project #2
    fs *= s2f;
    n2 = n2 * s2f * s2f;

    const int row = row0 + 4 * ty + i;
    const int b = row >> 10, s = row & 1023;
    const size_t bh = (size_t)(b * NH + head);
    const size_t outbase = (bh * SS + s) * DH + 4 * tx;
    float4 o;
    if (mat == 2) {
      const float gamma = 2.0f / fmaxf(1.0f - n2, 1e-15f);
      o.x = y[i][0]*fs*gamma; o.y = y[i][1]*fs*gamma; o.z = y[i][2]*fs*gamma; o.w = y[i][3]*fs*gamma;
      if (tx == 0) Stat[bh * SS + s] = gamma - 1.0f;
    } else {
      o.x = y[i][0]*fs; o.y = y[i][1]*fs; o.z = y[i][2]*fs; o.w = y[i][3]*fs;
      if (tx == 0) Stat[bh * SS + s] = n2;
    }
    *(float4*)(OutM + outbase) = o;
  }
}

// ---------------- K3: fp32 -> split-bf16 (hi/lo) convert; GV also transposed ----------------
// grid (16 s-tiles, 32 bh, 3 mat), 256 thr. mat 0/1: elementwise Q/K. mat 2: GV -> GVT[dh][s].
__global__ __launch_bounds__(256) void convert_kernel(
    const float* __restrict__ QKV,   // Q,K,GV contiguous, each [bh][s][dh]
    unsigned short* __restrict__ Qhi, unsigned short* __restrict__ Qlo,
    unsigned short* __restrict__ Khi, unsigned short* __restrict__ Klo,
    unsigned short* __restrict__ GThi, unsigned short* __restrict__ GTlo)
{
  const int st = blockIdx.x, bh = blockIdx.y, mat = blockIdx.z;
  const int tid = threadIdx.x;
  const size_t nQKV = (size_t)BB * NH * SS * DH;
  const float* src = QKV + (size_t)mat * nQKV + ((size_t)bh * SS + st * 64) * DH;
  __shared__ unsigned T[64][69];   // packed (lo<<16)|hi, padded stride

  if (mat < 2) {
    unsigned short* dh_ = ((mat == 0) ? Qhi : Khi) + ((size_t)bh * SS + st * 64) * DH;
    unsigned short* dl_ = ((mat == 0) ? Qlo : Klo) + ((size_t)bh * SS + st * 64) * DH;
    #pragma unroll
    for (int i = 0; i < 4; ++i) {
      const int g = tid + 256 * i;
      const int row = g >> 4, c4 = (g & 15) * 4;
      float4 v = *(const float4*)(src + row * DH + c4);
      float a[4] = {v.x, v.y, v.z, v.w};
      ushort4 hv, lv;
      unsigned short* hp = (unsigned short*)&hv;
      unsigned short* lp = (unsigned short*)&lv;
      #pragma unroll
      for (int j = 0; j < 4; ++j) {
        unsigned short hi = f2bf(a[j]);
        hp[j] = hi;
        lp[j] = f2bf(a[j] - bf2f(hi));
      }
      *(ushort4*)(dh_ + row * DH + c4) = hv;
      *(ushort4*)(dl_ + row * DH + c4) = lv;
    }
  } else {
    #pragma unroll
    for (int i = 0; i < 4; ++i) {
      const int g = tid + 256 * i;
      const int row = g >> 4, c4 = (g & 15) * 4;
      float4 v = *(const float4*)(src + row * DH + c4);
      float a[4] = {v.x, v.y, v.z, v.w};
      #pragma unroll
      for (int j = 0; j < 4; ++j) {
        unsigned short hi = f2bf(a[j]);
        unsigned short lo = f2bf(a[j] - bf2f(hi));
        T[row][c4 + j] = ((unsigned)lo << 16) | (unsigned)hi;
      }
    }
    __syncthreads();
    #pragma unroll
    for (int i = 0; i < 4; ++i) {
      const int g = tid + 256 * i;
      const int kb = g & 15, dhr = g >> 4;
      ushort4 hv, lv;
      unsigned short* hp = (unsigned short*)&hv;
      unsigned short* lp = (unsigned short*)&lv;
      #pragma unroll
      for (int j = 0; j < 4; ++j) {
        unsigned u = T[4 * kb + j][dhr];
        hp[j] = (unsigned short)(u & 0xFFFFu);
        lp[j] = (unsigned short)(u >> 16);
      }
      const size_t ob = ((size_t)bh * DH + dhr) * SS + st * 64 + 4 * kb;
      *(ushort4*)(GThi + ob) = hv;
      *(ushort4*)(GTlo + ob) = lv;
    }
  }
}

// ---------------- K4: MFMA flash-style hyperbolic attention ----------------
// exp(-acosh(1+e)) == 1/(1+e+sqrt(e(e+2))) exactly, and z in [1,~8] here, so no
// online max / per-element exp: accumulate unnormalized w = exp(mask)/z directly
// (the gyromidpoint is scale-invariant in the weights).
__global__ __launch_bounds__(256) void flash_attn_kernel(
    const unsigned short* __restrict__ Qhi, const unsigned short* __restrict__ Qlo,
    const unsigned short* __restrict__ Khi, const unsigned short* __restrict__ Klo,
    const unsigned short* __restrict__ GThi, const unsigned short* __restrict__ GTlo,
    const float* __restrict__ q2a, const float* __restrict__ k2a, const float* __restrict__ gm1a,
    const float* __restrict__ mask, float* __restrict__ out)
{
  constexpr int LDK = 72;                      // pad: stride 72 bf16 = 36 words -> conflict-free b128
  __shared__ unsigned short Ks_hi[64 * LDK];   // K tile; reused as P (per-wave 16-row slices)
  __shared__ unsigned short Ks_lo[64 * LDK];
  __shared__ unsigned short Gs_hi[64 * LDK];   // GV^T tile [dh][key]
  __shared__ unsigned short Gs_lo[64 * LDK];
  __shared__ float k2s[64], ik2s[64], gm1s[64], ems[64];

  const int qt = blockIdx.x, h = blockIdx.y, b = blockIdx.z;
  const int bh = b * NH + h;
  const int tid = threadIdx.x;
  const int wave = tid >> 6, lane = tid & 63;
  const int tx = lane & 15, quad = lane >> 4;
  const int r0 = qt * 64;

  // Q A-fragments: A[m=lane&15][k=quad*8+j], loop-invariant -> registers
  bf16x8 qa_h[2], qa_l[2];
  {
    const size_t qoff = ((size_t)bh * SS + r0 + 16 * wave + tx) * DH;
    #pragma unroll
    for (int kc = 0; kc < 2; ++kc) {
      qa_h[kc] = *(const bf16x8*)(Qhi + qoff + 32 * kc + 8 * quad);
      qa_l[kc] = *(const bf16x8*)(Qlo + qoff + 32 * kc + 8 * quad);
    }
  }
  float q2r[4], iq2[4];
  #pragma unroll
  for (int r = 0; r < 4; ++r) {
    q2r[r] = q2a[(size_t)bh * SS + r0 + 16 * wave + 4 * quad + r];
    iq2[r] = 2.0f / fmaxf(1.0f - q2r[r], 1e-15f);
  }

  const f32x4 zero4 = {0.f, 0.f, 0.f, 0.f};
  f32x4 oacc[4] = {zero4, zero4, zero4, zero4};
  float dden[4] = {0.f, 0.f, 0.f, 0.f};

  const int c0 = tid, c1 = tid + 256;
  const int sr0 = c0 >> 3, sc0 = (c0 & 7) * 8;
  const int sr1 = c1 >> 3, sc1 = (c1 & 7) * 8;

  for (int kt = 0; kt < 16; ++kt) {
    const int t0 = kt * 64;
    __syncthreads();                           // prev PV / P reads done
    {
      const size_t kb_ = ((size_t)bh * SS + t0) * DH;
      const size_t gb_ = (size_t)bh * DH * SS + t0;
      *(uint4*)&Ks_hi[sr0 * LDK + sc0] = *(const uint4*)(Khi + kb_ + (size_t)sr0 * DH + sc0);
      *(uint4*)&Ks_hi[sr1 * LDK + sc1] = *(const uint4*)(Khi + kb_ + (size_t)sr1 * DH + sc1);
      *(uint4*)&Ks_lo[sr0 * LDK + sc0] = *(const uint4*)(Klo + kb_ + (size_t)sr0 * DH + sc0);
      *(uint4*)&Ks_lo[sr1 * LDK + sc1] = *(const uint4*)(Klo + kb_ + (size_t)sr1 * DH + sc1);
      *(uint4*)&Gs_hi[sr0 * LDK + sc0] = *(const uint4*)(GThi + gb_ + (size_t)sr0 * SS + sc0);
      *(uint4*)&Gs_hi[sr1 * LDK + sc1] = *(const uint4*)(GThi + gb_ + (size_t)sr1 * SS + sc1);
      *(uint4*)&Gs_lo[sr0 * LDK + sc0] = *(const uint4*)(GTlo + gb_ + (size_t)sr0 * SS + sc0);
      *(uint4*)&Gs_lo[sr1 * LDK + sc1] = *(const uint4*)(GTlo + gb_ + (size_t)sr1 * SS + sc1);
      if (tid < 64) {
        float k2v = k2a[(size_t)bh * SS + t0 + tid];
        k2s[tid] = k2v;
        ik2s[tid] = 1.0f / fmaxf(1.0f - k2v, 1e-15f);
        gm1s[tid] = gm1a[(size_t)bh * SS + t0 + tid];
        ems[tid] = __expf(mask[(size_t)b * SS + t0 + tid]);
      }
    }
    __syncthreads();                           // tiles visible

    // QK^T: split-bf16, 3 products (hi*hi + hi*lo + lo*hi)
    f32x4 sacc[4] = {zero4, zero4, zero4, zero4};
    #pragma unroll
    for (int kc = 0; kc < 2; ++kc) {
      const int ko = 32 * kc + 8 * quad;
      #pragma unroll
      for (int nb = 0; nb < 4; ++nb) {
        bf16x8 kh = *(const bf16x8*)&Ks_hi[(16 * nb + tx) * LDK + ko];
        bf16x8 kl = *(const bf16x8*)&Ks_lo[(16 * nb + tx) * LDK + ko];
        sacc[nb] = __builtin_amdgcn_mfma_f32_16x16x32_bf16(qa_h[kc], kh, sacc[nb], 0, 0, 0);
        sacc[nb] = __builtin_amdgcn_mfma_f32_16x16x32_bf16(qa_h[kc], kl, sacc[nb], 0, 0, 0);
        sacc[nb] = __builtin_amdgcn_mfma_f32_16x16x32_bf16(qa_l[kc], kh, sacc[nb], 0, 0, 0);
      }
    }

    // distance -> unnormalized weight w = em / (1 + e + sqrt(e(e+2)))
    float pb[4][4];
    #pragma unroll
    for (int nb = 0; nb < 4; ++nb) {
      const int key = 16 * nb + tx;
      const float k2v = k2s[key], ikv = ik2s[key], emv = ems[key], gmv = gm1s[key];
      #pragma unroll
      for (int r = 0; r < 4; ++r) {
        float sv = sacc[nb][r];
        float num = fmaxf(fmaf(-2.0f, sv, q2r[r] + k2v), 1e-15f);
        float e = num * iq2[r] * ikv;
        float g = fmaf(e, e, e + e);
        float z = 1.0f + e + __builtin_amdgcn_sqrtf(g);
        float w = emv * __builtin_amdgcn_rcpf(z);
        pb[r][nb] = w;
        dden[r] = fmaf(w, gmv, dden[r]);       // denominator (fp32, per-lane partial)
      }
    }
    __syncthreads();                           // all waves done reading Ks fragments

    // write P (split-bf16) into Ks region; wave w owns rows [16w,16w+16) exclusively
    #pragma unroll
    for (int r = 0; r < 4; ++r) {
      const int prow = 16 * wave + 4 * quad + r;
      #pragma unroll
      for (int nb = 0; nb < 4; ++nb) {
        float w = pb[r][nb];
        unsigned short hi = f2bf(w);
        unsigned short lo = f2bf(w - bf2f(hi));
        Ks_hi[prow * LDK + 16 * nb + tx] = hi;
        Ks_lo[prow * LDK + 16 * nb + tx] = lo;
      }
    }
    // PV: same-wave LDS RAW only (rows disjoint per wave) -> no barrier needed
    #pragma unroll
    for (int kc = 0; kc < 2; ++kc) {
      const int ko = 32 * kc + 8 * quad;
      bf16x8 ph = *(const bf16x8*)&Ks_hi[(16 * wave + tx) * LDK + ko];
      bf16x8 pl = *(const bf16x8*)&Ks_lo[(16 * wave + tx) * LDK + ko];
      #pragma unroll
      for (int nb = 0; nb < 4; ++nb) {
        bf16x8 gh = *(const bf16x8*)&Gs_hi[(16 * nb + tx) * LDK + ko];
        bf16x8 gl = *(const bf16x8*)&Gs_lo[(16 * nb + tx) * LDK + ko];
        oacc[nb] = __builtin_amdgcn_mfma_f32_16x16x32_bf16(ph, gh, oacc[nb], 0, 0, 0);
        oacc[nb] = __builtin_amdgcn_mfma_f32_16x16x32_bf16(ph, gl, oacc[nb], 0, 0, 0);
        oacc[nb] = __builtin_amdgcn_mfma_f32_16x16x32_bf16(pl, gh, oacc[nb], 0, 0, 0);
      }
    }
  }

  // epilogue: gyromidpoint normalization + project, write [B,S,H*dh]
  #pragma unroll
  for (int r = 0; r < 4; ++r) {
    float d = fmaxf(xor_sum16(dden[r]), 1e-10f);
    float invd = 1.0f / d;
    float tm[4]; float sq = 0.f;
    #pragma unroll
    for (int nb = 0; nb < 4; ++nb) { tm[nb] = oacc[nb][r] * invd; sq = fmaf(tm[nb], tm[nb], sq); }
    sq = xor_sum16(sq);
    const float f = 1.0f / (1.0f + sqrtf(fmaxf(1.0f - sq, 1e-15f)));
    const float n2 = sq * f * f;
    const float n = fmaxf(sqrtf(n2), 1e-15f);
    const float s2 = (n > MAXN) ? (MAXN / n) : 1.0f;
    const float fs = f * s2;
    const int qrow = r0 + 16 * wave + 4 * quad + r;
    #pragma unroll
    for (int nb = 0; nb < 4; ++nb)
      out[((size_t)(b * SS + qrow)) * DD + h * DH + 16 * nb + tx] = tm[nb] * fs;
  }
}

// ---------------- host ----------------
extern "C" void kernel_launch(void* const* d_in, const int* in_sizes, int n_in,
                              void* d_out, int out_size, void* d_ws, size_t ws_size,
                              hipStream_t stream) {
  const float* hs   = (const float*)d_in[0];
  const float* mask = (const float*)d_in[1];
  const float* qz   = (const float*)d_in[2];
  const float* qr   = (const float*)d_in[3];
  const float* kz   = (const float*)d_in[4];
  const float* kr   = (const float*)d_in[5];
  const float* vz   = (const float*)d_in[6];
  const float* vr   = (const float*)d_in[7];
  float* out = (float*)d_out;

  float* ws = (float*)d_ws;
  const size_t nQKV = (size_t)BB * NH * SS * DH;   // 2,097,152
  const size_t nStat = (size_t)BB * NH * SS;       // 32,768
  float* Q   = ws;                   // Q,K,GV must stay contiguous (convert_kernel)
  float* K   = Q + nQKV;
  float* GV  = K + nQKV;
  float* q2  = GV + nQKV;
  float* k2  = q2 + nStat;
  float* gm1 = k2 + nStat;
  float* zn  = gm1 + nStat;          // 3*1024
  float* c2r = zn + 3 * DD;
  float* s2r = c2r + 3 * DD;
  float* cx2 = s2r + 3 * DD;         // 2048
  unsigned short* bbuf = (unsigned short*)(cx2 + 2048);  // 16B-aligned (offset 25,604,096 B)
  unsigned short* Qhi  = bbuf;
  unsigned short* Qlo  = Qhi  + nQKV;
  unsigned short* Khi  = Qlo  + nQKV;
  unsigned short* Klo  = Khi  + nQKV;
  unsigned short* GThi = Klo  + nQKV;
  unsigned short* GTlo = GThi + nQKV;

  col_stats_kernel<<<dim3(4, 3), 256, 0, stream>>>(qz, kz, vz, qr, kr, vr, zn, c2r, s2r);
  row_cx2_kernel<<<dim3(512), 256, 0, stream>>>(hs, cx2);
  gemm_poincare_kernel<<<dim3(32, 16, 3), 256, 0, stream>>>(
      hs, qz, kz, vz, zn, c2r, s2r, cx2, Q, K, GV, q2, k2, gm1);
  convert_kernel<<<dim3(16, BB * NH, 3), 256, 0, stream>>>(
      Q, Qhi, Qlo, Khi, Klo, GThi, GTlo);
  flash_attn_kernel<<<dim3(16, NH, BB), 256, 0, stream>>>(
      Qhi, Qlo, Khi, Klo, GThi, GTlo, q2, k2, gm1, mask, out);
}